// Round 6
// baseline (45.459 us; speedup 1.0000x reference)
//
#include <hip/hip_runtime.h>
#include <math.h>

#define TOKDIM   256
#define DD       768
#define HDIM     512
#define LOCALDIM 16384
#define FEATDIM  16640            // 16384 + 256
#define BB       64
#define THRESH   0.7f
#define ONEF     0x3f800000u      // bit pattern of 1.0f

// workspace float offsets
#define WS_GNT   0                            // [256][64] gn transposed
#define WS_INV   (TOKDIM*BB)                  // [64] 1/norm
#define WS_CELL  (WS_INV + BB)                // 1 uint barrier cell
#define WS_CELL_BYTES (WS_CELL * 4)
#define CELL_LEN 64

// Cross-block data: RELAXED/AGENT atomics (per-access coherent at the device
// coherence point) -> no cache-wide flush/invalidate needed anywhere.
__device__ __forceinline__ void st_agent(float* p, float v) {
    __hip_atomic_store(p, v, __ATOMIC_RELAXED, __HIP_MEMORY_SCOPE_AGENT);
}
__device__ __forceinline__ float ld_agent(const float* p) {
    return __hip_atomic_load((float*)p, __ATOMIC_RELAXED, __HIP_MEMORY_SCOPE_AGENT);
}

// NetVLAD local branch is identically 1.0 (softmax(axis=1).sum(axis=1) == 1),
// so feats = [inv * ones(16384), g/norm], norm = sqrt(16384 + ||g||^2).
// One block per batch: whole MLP is block-local; ONE 64-way global barrier.
__global__ __launch_bounds__(1024) void mega_kernel(
    const float* __restrict__ gtok, const float* __restrict__ b1,
    const float* __restrict__ W1,   const float* __restrict__ W2,
    const float* __restrict__ b2,   const int* __restrict__ kptr,
    float* __restrict__ feats, unsigned* __restrict__ maskU,
    float* __restrict__ ws,    unsigned* __restrict__ cell)
{
    const int b = blockIdx.x, t = threadIdx.x;

    __shared__ float xs[DD];
    __shared__ float hh[4][HDIM];     // layer-1 partials (4 d-slices)
    __shared__ float hs[HDIM];
    __shared__ float gg[4][TOKDIM];   // layer-2 partials (4 j-slices)
    __shared__ float gns[TOKDIM];     // this batch's gn (phase-C A operand)
    __shared__ float part[16][BB];    // sim partials
    __shared__ float red[4];

    // block 0 zeroes the mask; drained before its barrier arrival, and all
    // atomicOr writers pass the barrier after block 0's arrival -> ordered.
    if (b == 0)
        for (int i = t; i < BB * BB; i += 1024)
            __hip_atomic_store(maskU + i, 0u, __ATOMIC_RELAXED, __HIP_MEMORY_SCOPE_AGENT);

    if (t < DD) xs[t] = gtok[b * DD + t];
    __syncthreads();

    // ---- layer 1: thread (p = t&255 -> units 2p,2p+1; q = t>>8 -> 192-d slice)
    {
        const int p = t & 255, q = t >> 8;
        float h0 = 0.f, h1 = 0.f;
        const float2* w = (const float2*)(W1 + (size_t)(q * 192) * HDIM) + p;
        #pragma unroll 8
        for (int d = 0; d < 192; ++d) {
            const float x = xs[q * 192 + d];
            const float2 wv = *w;
            h0 = fmaf(x, wv.x, h0);
            h1 = fmaf(x, wv.y, h1);
            w += HDIM / 2;
        }
        hh[q][2 * p] = h0; hh[q][2 * p + 1] = h1;
    }
    __syncthreads();
    if (t < HDIM)
        hs[t] = fmaxf(b1[t] + hh[0][t] + hh[1][t] + hh[2][t] + hh[3][t], 0.f);
    __syncthreads();

    // ---- layer 2: thread (o = t&255; jq = t>>8 -> 128-j slice)
    {
        const int o = t & 255, jq = t >> 8;
        float s = 0.f;
        const float* w = W2 + (size_t)(jq * 128) * TOKDIM + o;
        #pragma unroll 8
        for (int j = 0; j < 128; ++j) { s = fmaf(hs[jq * 128 + j], *w, s); w += TOKDIM; }
        gg[jq][o] = s;
    }
    __syncthreads();

    // ---- norm + gn ----
    float g = 0.f;
    if (t < TOKDIM) {
        g = b2[t] + gg[0][t] + gg[1][t] + gg[2][t] + gg[3][t];
        float s2 = g * g;
        #pragma unroll
        for (int off = 32; off > 0; off >>= 1) s2 += __shfl_down(s2, off);
        if ((t & 63) == 0) red[t >> 6] = s2;
    }
    __syncthreads();
    const float ssq = red[0] + red[1] + red[2] + red[3];
    const float inv = 1.f / fmaxf(sqrtf((float)LOCALDIM + ssq), 1e-12f);
    if (t < TOKDIM) {
        const float gn = g * inv;
        gns[t] = gn;
        feats[(size_t)b * FEATDIM + LOCALDIM + t] = gn;
        st_agent(ws + WS_GNT + (size_t)t * BB + b, gn);
        if (t == 0) st_agent(ws + WS_INV + b, inv);
    }

    // ---- arrive -> fill (overlaps barrier skew) -> spin ----
    asm volatile("s_waitcnt vmcnt(0)" ::: "memory");
    __syncthreads();
    if (t == 0)
        __hip_atomic_fetch_add(cell, 1u, __ATOMIC_RELAXED, __HIP_MEMORY_SCOPE_AGENT);
    {
        float4* f4 = (float4*)(feats + (size_t)b * FEATDIM);
        const float4 v = make_float4(inv, inv, inv, inv);
        f4[t] = v; f4[t + 1024] = v; f4[t + 2048] = v; f4[t + 3072] = v;
    }
    if (t == 0) {
        while (__hip_atomic_load(cell, __ATOMIC_RELAXED, __HIP_MEMORY_SCOPE_AGENT) < (unsigned)BB)
            __builtin_amdgcn_s_sleep(1);
        asm volatile("" ::: "memory");
    }
    __syncthreads();

    // ---- phase C: sim row b; thread (q = t>>6 -> 16-d slice, j = t&63) ----
    {
        const int q = t >> 6, j = t & 63;
        float s = 0.f;
        const float* gT = ws + WS_GNT + (size_t)(q * 16) * BB + j;
        #pragma unroll 16
        for (int d = 0; d < 16; ++d) { s = fmaf(gns[q * 16 + d], ld_agent(gT), s); gT += BB; }
        part[q][j] = s;
    }
    __syncthreads();
    if (t < BB) {                             // wave 0: full 64-lane wave
        const float invj = ld_agent(ws + WS_INV + t);
        float dot = 0.f;
        #pragma unroll
        for (int q = 0; q < 16; ++q) dot += part[q][t];
        const float sv = (float)LOCALDIM * inv * invj + dot;
        int k = *kptr; if (k > BB) k = BB;
        float v = sv;
        unsigned long long rowbits = 0;
        for (int p = 0; p < k; ++p) {         // ties -> lowest index (jax top_k)
            float m = v;
            #pragma unroll
            for (int off = 32; off > 0; off >>= 1) m = fmaxf(m, __shfl_xor(m, off));
            const unsigned long long ball = __ballot(v == m);
            const int bi = __ffsll(ball) - 1;
            rowbits |= 1ull << bi;
            if (t == bi) v = -INFINITY;
            if (t == 0) atomicOr(&maskU[bi * BB + b], ONEF);   // mask[idx, row] = 1
        }
        const unsigned base =
            ((sv > THRESH) || (t == b) || ((rowbits >> t) & 1ull)) ? ONEF : 0u;
        if (base) atomicOr(&maskU[b * BB + t], base);          // row b (diag/topk/thresh)
    }
}

extern "C" void kernel_launch(void* const* d_in, const int* in_sizes, int n_in,
                              void* d_out, int out_size, void* d_ws, size_t ws_size,
                              hipStream_t stream) {
    const float* gtok = (const float*)d_in[1];
    const float* W1g  = (const float*)d_in[6];
    const float* b1g  = (const float*)d_in[7];
    const float* W2g  = (const float*)d_in[8];
    const float* b2g  = (const float*)d_in[9];
    const int*   kp   = (const int*)d_in[10];

    float*    feats = (float*)d_out;                              // [64, 16640]
    unsigned* maskU = (unsigned*)(feats + (size_t)BB * FEATDIM);  // [64,64] as bits
    float*    ws    = (float*)d_ws;
    unsigned* cell  = (unsigned*)((char*)d_ws + WS_CELL_BYTES);

    // zero the barrier cell (graph-legal memset node), then the single kernel
    hipMemsetAsync((void*)cell, 0, CELL_LEN, stream);
    hipLaunchKernelGGL(mega_kernel, dim3(BB), dim3(1024), 0, stream,
                       gtok, b1g, W1g, W2g, b2g, kp, feats, maskU, ws, cell);
}

// Round 7
// 41.142 us; speedup vs baseline: 1.1049x; 1.1049x over previous
//
#include <hip/hip_runtime.h>
#include <math.h>

#define TOKDIM   256
#define DD       768
#define HDIM     512
#define LOCALDIM 16384
#define FEATDIM  16640            // 16384 + 256
#define BB       64
#define THRESH   0.7f
#define ONEF     0x3f800000u      // bit pattern of 1.0f
#define NP       4                // blocks per batch (d-slices of 192)
#define DSLICE   192
#define GRID     256              // 64 batches x 4 parts = 1 block per CU

// workspace float offsets
#define WS_PH    0                            // [4][64][512] raw partial h
#define WS_GN    (NP*BB*HDIM)                 // [64][256] gn
#define WS_GNT   (WS_GN + BB*TOKDIM)          // [256][64] gn transposed
#define WS_INV   (WS_GNT + TOKDIM*BB)         // [64] 1/norm
#define WS_CELL  (WS_INV + BB)                // cells: [64] per-batch, [1] global
#define WS_CELL_BYTES (WS_CELL * 4)
#define CELL_LEN ((BB + 1) * 4)

// Cross-block data: RELAXED/AGENT atomics (per-access coherent at the device
// coherence point) -> no cache-wide flush/invalidate needed anywhere.
__device__ __forceinline__ void st_agent(float* p, float v) {
    __hip_atomic_store(p, v, __ATOMIC_RELAXED, __HIP_MEMORY_SCOPE_AGENT);
}
__device__ __forceinline__ float ld_agent(const float* p) {
    return __hip_atomic_load((float*)p, __ATOMIC_RELAXED, __HIP_MEMORY_SCOPE_AGENT);
}

// NetVLAD local branch is identically 1.0 (softmax(axis=1).sum(axis=1) == 1),
// so feats = [inv * ones(16384), g/norm], norm = sqrt(16384 + ||g||^2).
// 4 blocks per batch (192-d slices) -> short float4 load chains, all 256 CUs.
__global__ __launch_bounds__(1024) void mega_kernel(
    const float* __restrict__ gtok, const float* __restrict__ b1,
    const float* __restrict__ W1,   const float* __restrict__ W2,
    const float* __restrict__ b2,   const int* __restrict__ kptr,
    float* __restrict__ feats, unsigned* __restrict__ maskU,
    float* __restrict__ ws,    unsigned* __restrict__ bar)
{
    const int blk = blockIdx.x, t = threadIdx.x;
    const int b = blk >> 2, p = blk & 3;      // batch, d-part
    unsigned* cell1 = bar;                    // [64] per-batch, target NP
    unsigned* cell2 = bar + BB;               // [1]  global, target GRID

    __shared__ float xs[DSLICE];
    __shared__ float hh[8][HDIM];             // layer-1 partials (8 q-slices)
    __shared__ float hs[HDIM];
    __shared__ float gg[16][TOKDIM];          // layer-2 partials (16 jq-slices)
    __shared__ float gis[TOKDIM];             // phase-C row-i gn
    __shared__ float part[16][BB];            // sim partials
    __shared__ float red[4];

    // block 0 zeroes the mask; drained before its barrier arrivals, and all
    // phase-C atomicOr writers pass the global barrier after it -> ordered.
    if (blk == 0)
        for (int i = t; i < BB * BB; i += 1024)
            __hip_atomic_store(maskU + i, 0u, __ATOMIC_RELAXED, __HIP_MEMORY_SCOPE_AGENT);

    if (t < DSLICE) xs[t] = gtok[b * DD + p * DSLICE + t];
    __syncthreads();

    // ---- layer 1 (this block's 192 d): thread = units [4u4..4u4+3] x 24 d ----
    {
        const int u4 = t & 127, q = t >> 7;   // quad index, 24-d subslice
        const float4* w = (const float4*)W1 + (size_t)(p * DSLICE + q * 24) * 128 + u4;
        float4 a = make_float4(0.f, 0.f, 0.f, 0.f);
        #pragma unroll 8
        for (int d = 0; d < 24; ++d) {
            const float x = xs[q * 24 + d];
            const float4 wv = w[(size_t)d * 128];
            a.x = fmaf(x, wv.x, a.x); a.y = fmaf(x, wv.y, a.y);
            a.z = fmaf(x, wv.z, a.z); a.w = fmaf(x, wv.w, a.w);
        }
        hh[q][4*u4+0] = a.x; hh[q][4*u4+1] = a.y;
        hh[q][4*u4+2] = a.z; hh[q][4*u4+3] = a.w;
    }
    __syncthreads();
    if (t < HDIM) {
        float s = 0.f;
        #pragma unroll
        for (int q = 0; q < 8; ++q) s += hh[q][t];
        st_agent(ws + WS_PH + ((size_t)p * BB + b) * HDIM + t, s);   // raw partial
    }

    // ---- per-batch barrier (4 arrivals) ----
    asm volatile("s_waitcnt vmcnt(0)" ::: "memory");
    __syncthreads();
    if (t == 0)
        __hip_atomic_fetch_add(cell1 + b, 1u, __ATOMIC_RELAXED, __HIP_MEMORY_SCOPE_AGENT);
    if (t == 0) {
        while (__hip_atomic_load(cell1 + b, __ATOMIC_RELAXED, __HIP_MEMORY_SCOPE_AGENT) < (unsigned)NP)
            __builtin_amdgcn_s_sleep(1);
        asm volatile("" ::: "memory");
    }
    __syncthreads();

    // ---- h reduce + bias + ReLU (redundant x4 per batch, different CUs) ----
    if (t < HDIM) {
        float hsum = b1[t];
        #pragma unroll
        for (int pp = 0; pp < NP; ++pp)
            hsum += ld_agent(ws + WS_PH + ((size_t)pp * BB + b) * HDIM + t);
        hs[t] = fmaxf(hsum, 0.f);
    }
    __syncthreads();

    // ---- layer 2 (full, redundant x4): thread = outputs [4o4..] x 32 j ----
    {
        const int o4 = t & 63, jq = t >> 6;
        const float4* w = (const float4*)W2 + (size_t)(jq * 32) * 64 + o4;
        float4 a = make_float4(0.f, 0.f, 0.f, 0.f);
        #pragma unroll 8
        for (int j = 0; j < 32; ++j) {
            const float hv = hs[jq * 32 + j];
            const float4 wv = w[(size_t)j * 64];
            a.x = fmaf(hv, wv.x, a.x); a.y = fmaf(hv, wv.y, a.y);
            a.z = fmaf(hv, wv.z, a.z); a.w = fmaf(hv, wv.w, a.w);
        }
        gg[jq][4*o4+0] = a.x; gg[jq][4*o4+1] = a.y;
        gg[jq][4*o4+2] = a.z; gg[jq][4*o4+3] = a.w;
    }
    __syncthreads();

    // ---- norm + gn ----
    float g = 0.f;
    if (t < TOKDIM) {
        g = b2[t];
        #pragma unroll
        for (int jq = 0; jq < 16; ++jq) g += gg[jq][t];
        float s2 = g * g;
        #pragma unroll
        for (int off = 32; off > 0; off >>= 1) s2 += __shfl_down(s2, off);
        if ((t & 63) == 0) red[t >> 6] = s2;
    }
    __syncthreads();
    const float ssq = red[0] + red[1] + red[2] + red[3];
    const float inv = 1.f / fmaxf(sqrtf((float)LOCALDIM + ssq), 1e-12f);
    if (p == 0 && t < TOKDIM) {
        const float gn = g * inv;
        feats[(size_t)b * FEATDIM + LOCALDIM + t] = gn;
        st_agent(ws + WS_GN  + (size_t)b * TOKDIM + t, gn);
        st_agent(ws + WS_GNT + (size_t)t * BB + b, gn);
        if (t == 0) st_agent(ws + WS_INV + b, inv);
    }

    // ---- global barrier: arrive -> fill quarter (overlaps skew) -> spin ----
    asm volatile("s_waitcnt vmcnt(0)" ::: "memory");
    __syncthreads();
    if (t == 0)
        __hip_atomic_fetch_add(cell2, 1u, __ATOMIC_RELAXED, __HIP_MEMORY_SCOPE_AGENT);
    ((float4*)feats)[(size_t)b * (FEATDIM / 4) + p * 1024 + t] =
        make_float4(inv, inv, inv, inv);          // this block's 1/4 local fill
    if (blk >= BB) return;                        // only blocks 0..63 run phase C
    if (t == 0) {
        while (__hip_atomic_load(cell2, __ATOMIC_RELAXED, __HIP_MEMORY_SCOPE_AGENT) < (unsigned)GRID)
            __builtin_amdgcn_s_sleep(1);
        asm volatile("" ::: "memory");
    }
    __syncthreads();

    // ---- phase C: block i computes sim row i + top-k + mask ORs ----
    const int i = blk;
    if (t < TOKDIM) gis[t] = ld_agent(ws + WS_GN + (size_t)i * TOKDIM + t);
    __syncthreads();
    {
        const int q = t >> 6, j = t & 63;         // 16-d slice, column j
        float s = 0.f;
        #pragma unroll
        for (int d = 0; d < 16; ++d)
            s = fmaf(gis[q * 16 + d],
                     ld_agent(ws + WS_GNT + (size_t)(q * 16 + d) * BB + j), s);
        part[q][j] = s;
    }
    __syncthreads();
    if (t < BB) {                                 // wave 0: full 64-lane wave
        const float invi = ld_agent(ws + WS_INV + i);
        const float invj = ld_agent(ws + WS_INV + t);
        float dot = 0.f;
        #pragma unroll
        for (int q = 0; q < 16; ++q) dot += part[q][t];
        const float sv = (float)LOCALDIM * invi * invj + dot;
        int k = *kptr; if (k > BB) k = BB;
        float v = sv;
        unsigned long long rowbits = 0;
        for (int pp = 0; pp < k; ++pp) {          // ties -> lowest index (jax top_k)
            float m = v;
            #pragma unroll
            for (int off = 32; off > 0; off >>= 1) m = fmaxf(m, __shfl_xor(m, off));
            const unsigned long long ball = __ballot(v == m);
            const int bi = __ffsll(ball) - 1;
            rowbits |= 1ull << bi;
            if (t == bi) v = -INFINITY;
            if (t == 0) atomicOr(&maskU[bi * BB + i], ONEF);   // mask[idx, row] = 1
        }
        const unsigned base =
            ((sv > THRESH) || (t == i) || ((rowbits >> t) & 1ull)) ? ONEF : 0u;
        if (base) atomicOr(&maskU[i * BB + t], base);          // row i
    }
}

extern "C" void kernel_launch(void* const* d_in, const int* in_sizes, int n_in,
                              void* d_out, int out_size, void* d_ws, size_t ws_size,
                              hipStream_t stream) {
    const float* gtok = (const float*)d_in[1];
    const float* W1g  = (const float*)d_in[6];
    const float* b1g  = (const float*)d_in[7];
    const float* W2g  = (const float*)d_in[8];
    const float* b2g  = (const float*)d_in[9];
    const int*   kp   = (const int*)d_in[10];

    float*    feats = (float*)d_out;                              // [64, 16640]
    unsigned* maskU = (unsigned*)(feats + (size_t)BB * FEATDIM);  // [64,64] as bits
    float*    ws    = (float*)d_ws;
    unsigned* bar   = (unsigned*)((char*)d_ws + WS_CELL_BYTES);

    // zero the 65 barrier cells (graph-legal memset node), then the kernel
    hipMemsetAsync((void*)bar, 0, CELL_LEN, stream);
    hipLaunchKernelGGL(mega_kernel, dim3(GRID), dim3(1024), 0, stream,
                       gtok, b1g, W1g, W2g, b2g, kp, feats, maskU, ws, bar);
}

// Round 8
// 23.045 us; speedup vs baseline: 1.9726x; 1.7853x over previous
//
#include <hip/hip_runtime.h>
#include <math.h>

#define TOKDIM   256
#define DD       768
#define HDIM     512
#define LOCALDIM 16384
#define FEATDIM  16640            // 16384 + 256
#define BB       64
#define THRESH   0.7f
#define ONEF     0x3f800000u      // bit pattern of 1.0f
#define NP       4                // layer-1 d-parts per batch
#define DSLICE   192              // 768 / 4

// workspace float offsets (all plain cached memory; coherence via graph edges)
#define WS_PH    0                            // [4][64][512] partial h
#define WS_GNT   (NP*BB*HDIM)                 // [256][64] gn transposed
#define WS_INV   (WS_GNT + TOKDIM*BB)         // [64] 1/norm

// NetVLAD local branch is identically 1.0 (softmax(axis=1).sum(axis=1) == 1),
// so feats = [inv * ones(16384), g/norm], norm = sqrt(16384 + ||g||^2).

// ---- A1: layer-1 partial h. 256 blocks = 64 batches x 4 d-slices. ----
// thread: 4 units (float4) x 24 d -> 3 unroll-8 load groups, fully coalesced.
__global__ __launch_bounds__(1024) void kA1(
    const float* __restrict__ gtok, const float* __restrict__ W1,
    float* __restrict__ ws)
{
    __shared__ float xs[DSLICE];
    __shared__ float hh[8][HDIM];
    const int blk = blockIdx.x, t = threadIdx.x;
    const int b = blk >> 2, p = blk & 3;

    if (t < DSLICE) xs[t] = gtok[b * DD + p * DSLICE + t];
    __syncthreads();

    const int u4 = t & 127, q = t >> 7;       // unit-quad, 24-d subslice
    const float4* w = (const float4*)W1 + (size_t)(p * DSLICE + q * 24) * 128 + u4;
    float4 a = make_float4(0.f, 0.f, 0.f, 0.f);
    #pragma unroll 8
    for (int d = 0; d < 24; ++d) {
        const float x = xs[q * 24 + d];
        const float4 wv = w[(size_t)d * 128];
        a.x = fmaf(x, wv.x, a.x); a.y = fmaf(x, wv.y, a.y);
        a.z = fmaf(x, wv.z, a.z); a.w = fmaf(x, wv.w, a.w);
    }
    hh[q][4*u4+0] = a.x; hh[q][4*u4+1] = a.y;
    hh[q][4*u4+2] = a.z; hh[q][4*u4+3] = a.w;
    __syncthreads();
    if (t < HDIM) {
        float s = 0.f;
        #pragma unroll
        for (int qq = 0; qq < 8; ++qq) s += hh[qq][t];
        ws[WS_PH + ((size_t)p * BB + b) * HDIM + t] = s;
    }
}

// ---- A2: h-reduce + ReLU + layer 2 + norm + gn/gnT/inv + feats fill. ----
// 64 blocks (one per batch). Block 0 also zeroes the mask (plain stores,
// ordered before kB's atomicOrs by the graph edge).
__global__ __launch_bounds__(1024) void kA2(
    const float* __restrict__ b1, const float* __restrict__ W2,
    const float* __restrict__ b2, float* __restrict__ ws,
    float* __restrict__ feats,    unsigned* __restrict__ maskU)
{
    __shared__ float hs[HDIM];
    __shared__ float gg[16][TOKDIM];
    __shared__ float red[4];
    const int b = blockIdx.x, t = threadIdx.x;

    if (b == 0)
        for (int i = t; i < BB * BB; i += 1024) maskU[i] = 0u;

    if (t < HDIM) {
        float s = b1[t];
        #pragma unroll
        for (int p = 0; p < NP; ++p)
            s += ws[WS_PH + ((size_t)p * BB + b) * HDIM + t];
        hs[t] = fmaxf(s, 0.f);
    }
    __syncthreads();

    // layer 2: thread = 4 outputs (float4) x 32 j -> 4 unroll-8 load groups
    {
        const int o4 = t & 63, jq = t >> 6;
        const float4* w = (const float4*)W2 + (size_t)(jq * 32) * 64 + o4;
        float4 a = make_float4(0.f, 0.f, 0.f, 0.f);
        #pragma unroll 8
        for (int j = 0; j < 32; ++j) {
            const float hv = hs[jq * 32 + j];
            const float4 wv = w[(size_t)j * 64];
            a.x = fmaf(hv, wv.x, a.x); a.y = fmaf(hv, wv.y, a.y);
            a.z = fmaf(hv, wv.z, a.z); a.w = fmaf(hv, wv.w, a.w);
        }
        gg[jq][4*o4+0] = a.x; gg[jq][4*o4+1] = a.y;
        gg[jq][4*o4+2] = a.z; gg[jq][4*o4+3] = a.w;
    }
    __syncthreads();

    float g = 0.f;
    if (t < TOKDIM) {
        g = b2[t];
        #pragma unroll
        for (int q = 0; q < 16; ++q) g += gg[q][t];
        float s2 = g * g;
        #pragma unroll
        for (int off = 32; off > 0; off >>= 1) s2 += __shfl_down(s2, off);
        if ((t & 63) == 0) red[t >> 6] = s2;
    }
    __syncthreads();
    const float ssq = red[0] + red[1] + red[2] + red[3];
    const float inv = 1.f / fmaxf(sqrtf((float)LOCALDIM + ssq), 1e-12f);
    if (t < TOKDIM) {
        const float gn = g * inv;
        feats[(size_t)b * FEATDIM + LOCALDIM + t] = gn;
        ws[WS_GNT + (size_t)t * BB + b] = gn;
        if (t == 0) ws[WS_INV + b] = inv;
    }
    // local fill: 4096 float4 per row / 1024 threads = 4 coalesced stores
    float4* f4 = (float4*)(feats + (size_t)b * FEATDIM);
    const float4 v = make_float4(inv, inv, inv, inv);
    f4[t] = v; f4[t + 1024] = v; f4[t + 2048] = v; f4[t + 3072] = v;
}

// ---- B: block i = sim row i + top-k + idempotent mask ORs. 64 blocks. ----
__global__ __launch_bounds__(1024) void kB(
    const float* __restrict__ feats, const float* __restrict__ ws,
    const int* __restrict__ kptr,    unsigned* __restrict__ maskU)
{
    __shared__ float gis[TOKDIM];
    __shared__ float part[16][BB];
    const int i = blockIdx.x, t = threadIdx.x;

    if (t < TOKDIM) gis[t] = feats[(size_t)i * FEATDIM + LOCALDIM + t];
    __syncthreads();
    {
        const int q = t >> 6, j = t & 63;     // 16-d slice, column j
        float s = 0.f;
        #pragma unroll
        for (int d = 0; d < 16; ++d)
            s = fmaf(gis[q * 16 + d], ws[WS_GNT + (size_t)(q * 16 + d) * BB + j], s);
        part[q][j] = s;
    }
    __syncthreads();
    if (t < BB) {                             // wave 0: full 64-lane wave
        const float invi = ws[WS_INV + i], invj = ws[WS_INV + t];
        float dot = 0.f;
        #pragma unroll
        for (int q = 0; q < 16; ++q) dot += part[q][t];
        const float sv = (float)LOCALDIM * invi * invj + dot;
        int k = *kptr; if (k > BB) k = BB;
        float v = sv;
        unsigned long long rowbits = 0;
        for (int p = 0; p < k; ++p) {         // ties -> lowest index (jax top_k)
            float m = v;
            #pragma unroll
            for (int off = 32; off > 0; off >>= 1) m = fmaxf(m, __shfl_xor(m, off));
            const unsigned long long ball = __ballot(v == m);
            const int bi = __ffsll(ball) - 1;
            rowbits |= 1ull << bi;
            if (t == bi) v = -INFINITY;
            if (t == 0) atomicOr(&maskU[bi * BB + i], ONEF);   // mask[idx, row] = 1
        }
        const unsigned base =
            ((sv > THRESH) || (t == i) || ((rowbits >> t) & 1ull)) ? ONEF : 0u;
        if (base) atomicOr(&maskU[i * BB + t], base);          // row i
    }
}

extern "C" void kernel_launch(void* const* d_in, const int* in_sizes, int n_in,
                              void* d_out, int out_size, void* d_ws, size_t ws_size,
                              hipStream_t stream) {
    const float* gtok = (const float*)d_in[1];
    const float* W1g  = (const float*)d_in[6];
    const float* b1g  = (const float*)d_in[7];
    const float* W2g  = (const float*)d_in[8];
    const float* b2g  = (const float*)d_in[9];
    const int*   kp   = (const int*)d_in[10];

    float*    feats = (float*)d_out;                              // [64, 16640]
    unsigned* maskU = (unsigned*)(feats + (size_t)BB * FEATDIM);  // [64,64] as bits
    float*    ws    = (float*)d_ws;

    hipLaunchKernelGGL(kA1, dim3(256), dim3(1024), 0, stream, gtok, W1g, ws);
    hipLaunchKernelGGL(kA2, dim3(BB),  dim3(1024), 0, stream, b1g, W2g, b2g, ws, feats, maskU);
    hipLaunchKernelGGL(kB,  dim3(BB),  dim3(1024), 0, stream, feats, ws, kp, maskU);
}

// Round 9
// 20.359 us; speedup vs baseline: 2.2328x; 1.1319x over previous
//
#include <hip/hip_runtime.h>
#include <math.h>

#define TOKDIM   256
#define DD       768
#define HDIM     512
#define LOCALDIM 16384
#define FEATDIM  16640            // 16384 + 256
#define BB       64
#define THRESH   0.7f
#define ONEF     0x3f800000u      // bit pattern of 1.0f
#define GP       65               // gT LDS pad (stride 65: conflict-free rows+cols)

// NetVLAD local branch is identically 1.0 (softmax(axis=1).sum(axis=1) == 1),
// so feats = [inv * ones(16384), g/norm], norm = sqrt(16384 + ||g||^2), and
// sim_ij = (16384 + g_i.g_j) * inv_i * inv_j  (gn never materialized).

// ---- K1: 256 blocks = 64 batches x 4 unit-chunks of 128 h-units. ----
// Unit-split => full-d dot per unit => ReLU in-block => layer-2 partial g.
// Only the LINEAR g-sum crosses blocks (reduced redundantly in K2).
__global__ __launch_bounds__(1024) void k1_mlp(
    const float* __restrict__ gtok, const float* __restrict__ W1,
    const float* __restrict__ b1,   const float* __restrict__ W2,
    float* __restrict__ pg,         unsigned* __restrict__ maskU)
{
    __shared__ float  xs[DD];
    __shared__ float4 hh4[32][32];    // layer-1 partials: [d-slice][unit-quad]
    __shared__ float  hs[128];
    __shared__ float4 gg4[16][64];    // layer-2 partials: [unit-slice][out-quad]
    const int blk = blockIdx.x, t = threadIdx.x;
    const int b = blk >> 2, uc = blk & 3;

    if (blk == 0) {                   // zero mask; graph edge orders before K2
        maskU[t] = 0u; maskU[t + 1024] = 0u; maskU[t + 2048] = 0u; maskU[t + 3072] = 0u;
    }
    if (t < DD) xs[t] = gtok[b * DD + t];
    __syncthreads();

    // layer 1: thread = 4 units (float4) x 24-d slice -> 3 unroll-8 groups
    {
        const int u4 = t & 31, q = t >> 5;
        const float4* w = (const float4*)W1 + (size_t)(q * 24) * 128 + uc * 32 + u4;
        float4 a = make_float4(0.f, 0.f, 0.f, 0.f);
        #pragma unroll 8
        for (int d = 0; d < 24; ++d) {
            const float x = xs[q * 24 + d];
            const float4 wv = w[(size_t)d * 128];
            a.x = fmaf(x, wv.x, a.x); a.y = fmaf(x, wv.y, a.y);
            a.z = fmaf(x, wv.z, a.z); a.w = fmaf(x, wv.w, a.w);
        }
        hh4[q][u4] = a;
    }
    __syncthreads();
    if (t < 128) {
        const float* h = (const float*)hh4;
        float s = b1[uc * 128 + t];
        #pragma unroll
        for (int q = 0; q < 32; ++q) s += h[q * 128 + t];
        hs[t] = fmaxf(s, 0.f);        // ReLU on COMPLETE h (full 768-d dot)
    }
    __syncthreads();

    // layer 2 partial: thread = 4 outputs (float4) x 8-unit slice -> 1 group
    {
        const int o4 = t & 63, jq = t >> 6;
        const float4* w = (const float4*)W2 + (size_t)(uc * 128 + jq * 8) * 64 + o4;
        float4 a = make_float4(0.f, 0.f, 0.f, 0.f);
        #pragma unroll
        for (int j = 0; j < 8; ++j) {
            const float hv = hs[jq * 8 + j];
            const float4 wv = w[(size_t)j * 64];
            a.x = fmaf(hv, wv.x, a.x); a.y = fmaf(hv, wv.y, a.y);
            a.z = fmaf(hv, wv.z, a.z); a.w = fmaf(hv, wv.w, a.w);
        }
        gg4[jq][o4] = a;
    }
    __syncthreads();
    if (t < 256) {
        const float* g = (const float*)gg4;
        float s = 0.f;
        #pragma unroll
        for (int q = 0; q < 16; ++q) s += g[q * 256 + t];
        pg[((size_t)uc * BB + b) * TOKDIM + t] = s;   // [uc][b][256]
    }
}

// ---- K2: 64 blocks. Block i: full g-reduce for ALL batches (256 KB, L2-hot),
// all inv-norms, feats row i, sim row i, top-k, idempotent mask ORs. ----
__global__ __launch_bounds__(1024) void k2_simmask(
    const float* __restrict__ pg, const float* __restrict__ b2,
    const int* __restrict__ kptr, float* __restrict__ feats,
    unsigned* __restrict__ maskU)
{
    __shared__ float gT[TOKDIM][GP];   // g transposed, padded
    __shared__ float part[16][BB];
    __shared__ float invs[BB];
    const int i = blockIdx.x, t = threadIdx.x;

    // reduce g for all 64 batches: 16 iters x 1024 coalesced 4-way loads
    #pragma unroll
    for (int it = 0; it < 16; ++it) {
        const int idx = it * 1024 + t;
        const int j = idx >> 8, d = idx & 255;
        const float v = b2[d]
            + pg[((size_t)0 * BB + j) * TOKDIM + d]
            + pg[((size_t)1 * BB + j) * TOKDIM + d]
            + pg[((size_t)2 * BB + j) * TOKDIM + d]
            + pg[((size_t)3 * BB + j) * TOKDIM + d];
        gT[d][j] = v;
    }
    __syncthreads();

    // ||g_j||^2 partials -> inv norms
    {
        const int q = t >> 6, j = t & 63;
        float s = 0.f;
        #pragma unroll
        for (int dd = 0; dd < 16; ++dd) { const float v = gT[q * 16 + dd][j]; s = fmaf(v, v, s); }
        part[q][j] = s;
    }
    __syncthreads();
    if (t < BB) {
        float ssq = 0.f;
        #pragma unroll
        for (int q = 0; q < 16; ++q) ssq += part[q][t];
        invs[t] = 1.f / fmaxf(sqrtf((float)LOCALDIM + ssq), 1e-12f);
    }
    __syncthreads();
    const float inv = invs[i];

    // feats row i: 16384-wide inv fill (4 float4/thread) + normalized g
    {
        float4* f4 = (float4*)(feats + (size_t)i * FEATDIM);
        const float4 v = make_float4(inv, inv, inv, inv);
        f4[t] = v; f4[t + 1024] = v; f4[t + 2048] = v; f4[t + 3072] = v;
        if (t < TOKDIM) feats[(size_t)i * FEATDIM + LOCALDIM + t] = gT[t][i] * inv;
    }

    // sim row i partials: gT[d][i] broadcast, gT[d][j] stride-1 (2/bank, free)
    {
        const int q = t >> 6, j = t & 63;
        float s = 0.f;
        #pragma unroll
        for (int dd = 0; dd < 16; ++dd)
            s = fmaf(gT[q * 16 + dd][i], gT[q * 16 + dd][j], s);
        part[q][j] = s;
    }
    __syncthreads();
    if (t < BB) {                      // wave 0: full 64-lane wave
        float dot = 0.f;
        #pragma unroll
        for (int q = 0; q < 16; ++q) dot += part[q][t];
        const float sv = ((float)LOCALDIM + dot) * inv * invs[t];
        int k = *kptr; if (k > BB) k = BB;
        float v = sv;
        unsigned long long rowbits = 0;
        for (int p = 0; p < k; ++p) {  // ties -> lowest index (jax top_k)
            float m = v;
            #pragma unroll
            for (int off = 32; off > 0; off >>= 1) m = fmaxf(m, __shfl_xor(m, off));
            const unsigned long long ball = __ballot(v == m);
            const int bi = __ffsll(ball) - 1;
            rowbits |= 1ull << bi;
            if (t == bi) v = -INFINITY;
            if (t == 0) atomicOr(&maskU[bi * BB + i], ONEF);   // mask[idx, row] = 1
        }
        const unsigned base =
            ((sv > THRESH) || (t == i) || ((rowbits >> t) & 1ull)) ? ONEF : 0u;
        if (base) atomicOr(&maskU[i * BB + t], base);          // row i
    }
}

extern "C" void kernel_launch(void* const* d_in, const int* in_sizes, int n_in,
                              void* d_out, int out_size, void* d_ws, size_t ws_size,
                              hipStream_t stream) {
    const float* gtok = (const float*)d_in[1];
    const float* W1g  = (const float*)d_in[6];
    const float* b1g  = (const float*)d_in[7];
    const float* W2g  = (const float*)d_in[8];
    const float* b2g  = (const float*)d_in[9];
    const int*   kp   = (const int*)d_in[10];

    float*    feats = (float*)d_out;                              // [64, 16640]
    unsigned* maskU = (unsigned*)(feats + (size_t)BB * FEATDIM);  // [64,64] as bits
    float*    pg    = (float*)d_ws;                               // [4][64][256]

    hipLaunchKernelGGL(k1_mlp,     dim3(256), dim3(1024), 0, stream,
                       gtok, W1g, b1g, W2g, pg, maskU);
    hipLaunchKernelGGL(k2_simmask, dim3(BB),  dim3(1024), 0, stream,
                       pg, b2g, kp, feats, maskU);
}